// Round 9
// baseline (944.943 us; speedup 1.0000x reference)
//
#include <hip/hip_runtime.h>
#include <hip/hip_bf16.h>
#include <stdint.h>
#include <stddef.h>

typedef __attribute__((ext_vector_type(8))) short short8;
typedef __attribute__((ext_vector_type(4))) short short4v;
typedef __attribute__((ext_vector_type(4))) float f32x4;

#define NB 2048
#define HD 512
#define SD 256

__device__ __forceinline__ short f2bf(float x) {
  __hip_bfloat16 h = __float2bfloat16(x);
  return *reinterpret_cast<short*>(&h);
}

__device__ __forceinline__ float fast_tanh(float x) {
  x = fminf(fmaxf(x, -15.f), 15.f);
  float e = __expf(2.f * x);
  return __fdividef(e - 1.f, e + 1.f);
}

// ---- Wtb[kb][j][kk] = bf16(W[kb*32+kk][j]) : k-blocked transposed layout ----
__global__ __launch_bounds__(256) void wconv_kernel(const float* __restrict__ W,
                                                    short* __restrict__ Wtb) {
  __shared__ float tile[32][33];
  const int bx = blockIdx.x;
  const int tk0 = (bx & 15) * 32;
  const int tj0 = (bx >> 4) * 32;
  const int lx = threadIdx.x & 31;
  const int ly = threadIdx.x >> 5;
  for (int r = 0; r < 4; ++r) {
    int yy = ly + r * 8;
    tile[yy][lx] = W[(size_t)(tk0 + yy) * HD + tj0 + lx];
  }
  __syncthreads();
  const int kb = tk0 >> 5;
  for (int r = 0; r < 4; ++r) {
    int yy = ly + r * 8;
    Wtb[(size_t)kb * (HD * 32) + (size_t)(tj0 + yy) * 32 + lx] = f2bf(tile[lx][yy]);
  }
}

// ---- alignment[n][s] = sum_j tanh( sum_k hs[n,k,s]*W[k,j] + b[j] ) * c[j] ----
// Block = 128 s x FULL 512 j (A read once). 1024 threads = 16 waves
// (2 s-halves x 8 j-strips of 64), wave tile 64s x 64j -> acc[4][4] = 64 VGPR
// -> ~116 total -> 4 waves/SIMD. BOTH A (8 KB bf16) and W (32 KB bf16) staged
// in LDS per 32-k step, double-buffered (80 KB). W L2 traffic: one fetch per
// block-step (2.1 GB total, was 16.8 GB per-wave). Stage issue placed before
// the MFMA cluster; pack/ds_write after it (loads covered by ~1240 cyc of
// MFMA per SIMD); single __syncthreads per step with an empty vmcnt drain.
__global__ void __launch_bounds__(1024, 4)
align_kernel(const float* __restrict__ hs, const short* __restrict__ Wtb,
             const float* __restrict__ bias, const float* __restrict__ ctxv,
             float* __restrict__ align_out)
{
  __shared__ short As[2][128 * 32];   // 8 KB per buffer
  __shared__ short Ws[2][512 * 32];   // 32 KB per buffer
  __shared__ float abuf[128];

  const int tid = threadIdx.x;
  const int n = blockIdx.x >> 1;
  const int s0 = (blockIdx.x & 1) * 128;
  const float* hsn = hs + (size_t)n * (HD * SD) + s0;

  if (tid < 128) abuf[tid] = 0.f;

  // A stage map: thread -> (s, k-quad): 4 k-strided fp32 -> short4 b64 write
  const int a_s = tid >> 3;            // 0..127
  const int a_o = (tid >> 1) & 3;      // k-octet 0..3
  const int a_h = tid & 1;             // k-quad within octet
  const int a_k = a_o * 8 + a_h * 4;
  // W stage map: thread -> (j, 2 octets): 2x short8 (32 B) global + b128 writes
  const int w_j = tid >> 1;            // 0..511
  const int w_o = (tid & 1) * 2;       // octets {0,1} or {2,3}

  // prologue: stage kt=0 into buffer 0
  {
    const float* src = hsn + (size_t)a_k * SD + a_s;
    short4v pk;
    #pragma unroll
    for (int e = 0; e < 4; ++e) pk[e] = f2bf(src[(size_t)e * SD]);
    *(short4v*)&As[0][a_s * 32 + a_k] = pk;

    const short* wsrc = Wtb + (size_t)w_j * 32 + w_o * 8;
    *(short8*)&Ws[0][w_j * 32 + w_o * 8] = *(const short8*)(wsrc);
    *(short8*)&Ws[0][w_j * 32 + w_o * 8 + 8] = *(const short8*)(wsrc + 8);
  }
  __syncthreads();

  const int lane = tid & 63;
  const int wid = tid >> 6;      // 0..15
  const int wm = wid >> 3;       // 0..1 : 64-s half
  const int wj = wid & 7;        // 0..7 : 64-j strip
  const int l15 = lane & 15;
  const int lg = lane >> 4;

  f32x4 acc[4][4];
  #pragma unroll
  for (int i = 0; i < 4; ++i)
    #pragma unroll
    for (int p = 0; p < 4; ++p)
      acc[i][p] = (f32x4){0.f, 0.f, 0.f, 0.f};

  const int aoff = (wm * 64 + l15) * 32 + lg * 8;   // + i*16*32
  const int woff = (wj * 64 + l15) * 32 + lg * 8;   // + p*16*32

  for (int kt = 0; kt < 16; ++kt) {
    const int cur = kt & 1;

    // 1) issue next-step global stage loads (A: 4 fp32, W: 2x short8)
    float av[4];
    short8 wv0, wv1;
    if (kt < 15) {
      const float* src = hsn + (size_t)((kt + 1) * 32 + a_k) * SD + a_s;
      #pragma unroll
      for (int e = 0; e < 4; ++e) av[e] = src[(size_t)e * SD];
      const short* wsrc = Wtb + (size_t)(kt + 1) * (HD * 32) + w_j * 32 + w_o * 8;
      wv0 = *(const short8*)(wsrc);
      wv1 = *(const short8*)(wsrc + 8);
    }

    // 2) W fragments from LDS (b128, even 8-slots/bank)
    short8 wf[4];
    #pragma unroll
    for (int p = 0; p < 4; ++p)
      wf[p] = *(const short8*)&Ws[cur][woff + p * (16 * 32)];

    // 3) MFMA: D[j][s] += Wfrag(16j x 32k) * Afrag(32k x 16s)
    #pragma unroll
    for (int i = 0; i < 4; ++i) {
      short8 af = *(const short8*)&As[cur][aoff + i * (16 * 32)];
      #pragma unroll
      for (int p = 0; p < 4; ++p)
        acc[i][p] = __builtin_amdgcn_mfma_f32_16x16x32_bf16(wf[p], af, acc[i][p], 0, 0, 0);
    }

    // 4) pack + LDS-write the prefetched tile into the other buffer
    if (kt < 15) {
      const int nxt = cur ^ 1;
      short4v pk;
      #pragma unroll
      for (int e = 0; e < 4; ++e) pk[e] = f2bf(av[e]);
      *(short4v*)&As[nxt][a_s * 32 + a_k] = pk;
      *(short8*)&Ws[nxt][w_j * 32 + w_o * 8] = wv0;
      *(short8*)&Ws[nxt][w_j * 32 + w_o * 8 + 8] = wv1;
    }
    __syncthreads();
  }

  // epilogue: D rows = j (lg*4 + r), cols = s (l15). tanh + *c, reduce j.
  float part[4] = {0.f, 0.f, 0.f, 0.f};
  #pragma unroll
  for (int p = 0; p < 4; ++p) {
    const int j = wj * 64 + p * 16 + lg * 4;
    f32x4 bv = *(const f32x4*)(bias + j);
    f32x4 cv = *(const f32x4*)(ctxv + j);
    #pragma unroll
    for (int i = 0; i < 4; ++i)
      #pragma unroll
      for (int r = 0; r < 4; ++r)
        part[i] += fast_tanh(acc[i][p][r] + bv[r]) * cv[r];
  }
  #pragma unroll
  for (int i = 0; i < 4; ++i) {
    part[i] += __shfl_xor(part[i], 16);
    part[i] += __shfl_xor(part[i], 32);
  }
  if (lg == 0) {
    #pragma unroll
    for (int i = 0; i < 4; ++i)
      atomicAdd(&abuf[wm * 64 + i * 16 + l15], part[i]);
  }
  __syncthreads();
  if (tid < 128) align_out[(size_t)n * SD + s0 + tid] = abuf[tid];
}

// ---- softmax over s + context[n,h] = sum_s attn[s]*hs[n,h,s] ----
__global__ __launch_bounds__(256) void ctx_kernel(const float* __restrict__ hs,
                                                  const float* __restrict__ align_in,
                                                  float* __restrict__ out)
{
  __shared__ __align__(16) float attn_s[256];
  __shared__ float red[8];
  const int n = blockIdx.x;
  const int t = threadIdx.x;
  const int lane = t & 63, wid = t >> 6;

  float a = align_in[(size_t)n * 256 + t];
  float m = a;
  #pragma unroll
  for (int off = 32; off; off >>= 1) m = fmaxf(m, __shfl_xor(m, off));
  if (lane == 0) red[wid] = m;
  __syncthreads();
  m = fmaxf(fmaxf(red[0], red[1]), fmaxf(red[2], red[3]));
  float e = __expf(a - m);
  float s = e;
  #pragma unroll
  for (int off = 32; off; off >>= 1) s += __shfl_xor(s, off);
  if (lane == 0) red[4 + wid] = s;
  __syncthreads();
  s = red[4] + red[5] + red[6] + red[7];
  attn_s[t] = e / s;
  __syncthreads();

  const int grp = t & 7;      // s-chunk of 32
  const int hrow = t >> 3;    // 0..31
  float av[32];
  #pragma unroll
  for (int u = 0; u < 8; ++u) {
    float4 v = *(const float4*)&attn_s[grp * 32 + u * 4];
    av[4*u+0] = v.x; av[4*u+1] = v.y; av[4*u+2] = v.z; av[4*u+3] = v.w;
  }
  const float* hb = hs + (size_t)n * (HD * SD) + grp * 32;
  for (int it = 0; it < 16; ++it) {
    const int h = it * 32 + hrow;
    const float4* p = (const float4*)(hb + (size_t)h * SD);
    float acc = 0.f;
    #pragma unroll
    for (int u = 0; u < 8; ++u) {
      float4 v = p[u];
      acc += av[4*u+0]*v.x + av[4*u+1]*v.y + av[4*u+2]*v.z + av[4*u+3]*v.w;
    }
    acc += __shfl_xor(acc, 1);
    acc += __shfl_xor(acc, 2);
    acc += __shfl_xor(acc, 4);
    if (grp == 0) out[(size_t)n * HD + h] = acc;
  }
}

extern "C" void kernel_launch(void* const* d_in, const int* in_sizes, int n_in,
                              void* d_out, int out_size, void* d_ws, size_t ws_size,
                              hipStream_t stream) {
  (void)in_sizes; (void)n_in; (void)out_size; (void)ws_size;
  const float* hs = (const float*)d_in[0];
  const float* W  = (const float*)d_in[1];
  const float* b  = (const float*)d_in[2];
  const float* c  = (const float*)d_in[3];
  float* out = (float*)d_out;

  float* align_ws = (float*)d_ws;                                  // 2 MB
  short* Wtb = (short*)((char*)d_ws + (size_t)NB * SD * 4);        // 512 KB

  wconv_kernel<<<256, 256, 0, stream>>>(W, Wtb);
  align_kernel<<<NB * 2, 1024, 0, stream>>>(hs, Wtb, b, c, align_ws);
  ctx_kernel<<<NB, 256, 0, stream>>>(hs, align_ws, out);
}

// Round 10
// 806.315 us; speedup vs baseline: 1.1719x; 1.1719x over previous
//
#include <hip/hip_runtime.h>
#include <hip/hip_bf16.h>
#include <stdint.h>
#include <stddef.h>

typedef __attribute__((ext_vector_type(8))) short short8;
typedef __attribute__((ext_vector_type(4))) short short4v;
typedef __attribute__((ext_vector_type(4))) float f32x4;
typedef __attribute__((ext_vector_type(16))) float f32x16;

#define NB 2048
#define HD 512
#define SD 256

#define AS_STR 24   // shorts per A-tile row (16 k + 8 pad) -> 48 B
#define WS_STR 24   // shorts per W-tile row

__device__ __forceinline__ short f2bf(float x) {
  __hip_bfloat16 h = __float2bfloat16(x);
  return *reinterpret_cast<short*>(&h);
}

__device__ __forceinline__ float fast_tanh(float x) {
  x = fminf(fmaxf(x, -15.f), 15.f);
  float e = __expf(2.f * x);
  return __fdividef(e - 1.f, e + 1.f);
}

// ---- Wtb16[kb][j][kk] = bf16(W[kb*16+kk][j]), kb in [0,32) ----
__global__ __launch_bounds__(256) void wconv_kernel(const float* __restrict__ W,
                                                    short* __restrict__ Wtb16) {
  __shared__ float tile[32][33];
  const int bx = blockIdx.x;
  const int tk0 = (bx & 15) * 32;
  const int tj0 = (bx >> 4) * 32;
  const int lx = threadIdx.x & 31;
  const int ly = threadIdx.x >> 5;
  for (int r = 0; r < 4; ++r) {
    int yy = ly + r * 8;
    tile[yy][lx] = W[(size_t)(tk0 + yy) * HD + tj0 + lx];
  }
  __syncthreads();
  for (int r = 0; r < 4; ++r) {
    int yy = ly + r * 8;
    const int k = tk0 + lx;
    Wtb16[(size_t)(k >> 4) * (HD * 16) + (size_t)(tj0 + yy) * 16 + (k & 15)] =
        f2bf(tile[lx][yy]);
  }
}

// ---- alignment[n][s] = sum_j tanh( sum_k hs[n,k,s]*W[k,j] + b[j] ) * c[j] ----
// Block = 64 s x FULL 512 j, 512 threads = 8 waves (j-strips of 64).
// Wave tile 64s x 64j via 32x32x16 MFMA: acc[2][2] f32x16 = 64 VGPR ->
// ~116 total -> 4 waves/SIMD -> TWO blocks resident per CU (LDS 54 KB):
// cross-block overlap hides the per-step barrier + load latency.
// K-step 16, A (3 KB) + W (24 KB) double-buffered in LDS, 48 B row stride
// (2 lanes/bank-pair on all b128 = conflict-free floor).
__global__ void __launch_bounds__(512, 4)
align_kernel(const float* __restrict__ hs, const short* __restrict__ Wtb16,
             const float* __restrict__ bias, const float* __restrict__ ctxv,
             float* __restrict__ align_out)
{
  __shared__ short As[2][64 * AS_STR];    // 3 KB / buf
  __shared__ short Ws[2][512 * WS_STR];   // 24 KB / buf
  __shared__ float abuf[64];

  const int tid = threadIdx.x;
  const int n = blockIdx.x >> 2;
  const int s0 = (blockIdx.x & 3) * 64;
  const float* hsn = hs + (size_t)n * (HD * SD) + s0;

  if (tid < 64) abuf[tid] = 0.f;

  // A stage map (waves 0-3): thread -> (s, k-quad of 4)
  const int a_s = tid & 63;
  const int a_kq = (tid >> 6) & 3;        // k = a_kq*4 + e
  // W stage map (all 512): thread -> j row (16 shorts = 32 B contiguous)
  const int w_j = tid;

  // prologue: stage kt=0 into buffer 0
  if (tid < 256) {
    const float* src = hsn + (size_t)(a_kq * 4) * SD + a_s;
    short4v pk;
    pk[0] = f2bf(src[0]); pk[1] = f2bf(src[SD]);
    pk[2] = f2bf(src[2 * SD]); pk[3] = f2bf(src[3 * SD]);
    *(short4v*)&As[0][a_s * AS_STR + a_kq * 4] = pk;
  }
  {
    const short* wsrc = Wtb16 + (size_t)w_j * 16;
    *(short8*)&Ws[0][w_j * WS_STR] = *(const short8*)wsrc;
    *(short8*)&Ws[0][w_j * WS_STR + 8] = *(const short8*)(wsrc + 8);
  }
  __syncthreads();

  const int lane = tid & 63;
  const int wid = tid >> 6;
  const int jb = wid * 64;
  const int l31 = lane & 31;
  const int hg = lane >> 5;               // k-half: k = hg*8 + e

  f32x16 acc[2][2];
  #pragma unroll
  for (int i = 0; i < 2; ++i)
    #pragma unroll
    for (int p = 0; p < 2; ++p)
      #pragma unroll
      for (int q = 0; q < 16; ++q) acc[i][p][q] = 0.f;

  const int afo = l31 * AS_STR + hg * 8;                 // + i*32*AS_STR
  const int wfo = (jb + l31) * WS_STR + hg * 8;          // + p*32*WS_STR

  for (int kt = 0; kt < 32; ++kt) {
    const int cur = kt & 1;

    // 1) issue next-step global stage loads
    float av[4];
    short8 wv0, wv1;
    if (kt < 31) {
      if (tid < 256) {
        const float* src = hsn + (size_t)((kt + 1) * 16 + a_kq * 4) * SD + a_s;
        #pragma unroll
        for (int e = 0; e < 4; ++e) av[e] = src[(size_t)e * SD];
      }
      const short* wsrc = Wtb16 + (size_t)(kt + 1) * (HD * 16) + (size_t)w_j * 16;
      wv0 = *(const short8*)wsrc;
      wv1 = *(const short8*)(wsrc + 8);
    }

    // 2) fragments from LDS (b128, conflict-free)
    short8 wf0 = *(const short8*)&Ws[cur][wfo];
    short8 wf1 = *(const short8*)&Ws[cur][wfo + 32 * WS_STR];
    short8 af0 = *(const short8*)&As[cur][afo];
    short8 af1 = *(const short8*)&As[cur][afo + 32 * AS_STR];

    // 3) MFMA: D[j][s] += Wfrag(32j x 16k) * Afrag(16k x 32s)
    __builtin_amdgcn_s_setprio(1);
    acc[0][0] = __builtin_amdgcn_mfma_f32_32x32x16_bf16(wf0, af0, acc[0][0], 0, 0, 0);
    acc[0][1] = __builtin_amdgcn_mfma_f32_32x32x16_bf16(wf1, af0, acc[0][1], 0, 0, 0);
    acc[1][0] = __builtin_amdgcn_mfma_f32_32x32x16_bf16(wf0, af1, acc[1][0], 0, 0, 0);
    acc[1][1] = __builtin_amdgcn_mfma_f32_32x32x16_bf16(wf1, af1, acc[1][1], 0, 0, 0);
    __builtin_amdgcn_s_setprio(0);

    // 4) pack + LDS-write prefetched tile into the other buffer
    if (kt < 31) {
      const int nxt = cur ^ 1;
      if (tid < 256) {
        short4v pk;
        #pragma unroll
        for (int e = 0; e < 4; ++e) pk[e] = f2bf(av[e]);
        *(short4v*)&As[nxt][a_s * AS_STR + a_kq * 4] = pk;
      }
      *(short8*)&Ws[nxt][w_j * WS_STR] = wv0;
      *(short8*)&Ws[nxt][w_j * WS_STR + 8] = wv1;
    }
    __syncthreads();
  }

  // epilogue: D col = s = l31 (+i*32), row(q) = (q&3) + 8*(q>>2) + 4*hg (+p*32).
  float part0 = 0.f, part1 = 0.f;
  #pragma unroll
  for (int p = 0; p < 2; ++p) {
    const int jfr = jb + p * 32 + hg * 4;
    #pragma unroll
    for (int g = 0; g < 4; ++g) {
      const int j4 = jfr + g * 8;
      f32x4 bv = *(const f32x4*)(bias + j4);
      f32x4 cv = *(const f32x4*)(ctxv + j4);
      #pragma unroll
      for (int r = 0; r < 4; ++r) {
        const int q = g * 4 + r;
        part0 += fast_tanh(acc[0][p][q] + bv[r]) * cv[r];
        part1 += fast_tanh(acc[1][p][q] + bv[r]) * cv[r];
      }
    }
  }
  part0 += __shfl_xor(part0, 32);
  part1 += __shfl_xor(part1, 32);
  if (lane < 32) {
    atomicAdd(&abuf[l31], part0);
    atomicAdd(&abuf[32 + l31], part1);
  }
  __syncthreads();
  if (tid < 64) align_out[(size_t)n * SD + s0 + tid] = abuf[tid];
}

// ---- softmax over s + context[n,h] = sum_s attn[s]*hs[n,h,s] ----
__global__ __launch_bounds__(256) void ctx_kernel(const float* __restrict__ hs,
                                                  const float* __restrict__ align_in,
                                                  float* __restrict__ out)
{
  __shared__ __align__(16) float attn_s[256];
  __shared__ float red[8];
  const int n = blockIdx.x;
  const int t = threadIdx.x;
  const int lane = t & 63, wid = t >> 6;

  float a = align_in[(size_t)n * 256 + t];
  float m = a;
  #pragma unroll
  for (int off = 32; off; off >>= 1) m = fmaxf(m, __shfl_xor(m, off));
  if (lane == 0) red[wid] = m;
  __syncthreads();
  m = fmaxf(fmaxf(red[0], red[1]), fmaxf(red[2], red[3]));
  float e = __expf(a - m);
  float s = e;
  #pragma unroll
  for (int off = 32; off; off >>= 1) s += __shfl_xor(s, off);
  if (lane == 0) red[4 + wid] = s;
  __syncthreads();
  s = red[4] + red[5] + red[6] + red[7];
  attn_s[t] = e / s;
  __syncthreads();

  const int grp = t & 7;      // s-chunk of 32
  const int hrow = t >> 3;    // 0..31
  float av[32];
  #pragma unroll
  for (int u = 0; u < 8; ++u) {
    float4 v = *(const float4*)&attn_s[grp * 32 + u * 4];
    av[4*u+0] = v.x; av[4*u+1] = v.y; av[4*u+2] = v.z; av[4*u+3] = v.w;
  }
  const float* hb = hs + (size_t)n * (HD * SD) + grp * 32;
  for (int it = 0; it < 16; ++it) {
    const int h = it * 32 + hrow;
    const float4* p = (const float4*)(hb + (size_t)h * SD);
    float acc = 0.f;
    #pragma unroll
    for (int u = 0; u < 8; ++u) {
      float4 v = p[u];
      acc += av[4*u+0]*v.x + av[4*u+1]*v.y + av[4*u+2]*v.z + av[4*u+3]*v.w;
    }
    acc += __shfl_xor(acc, 1);
    acc += __shfl_xor(acc, 2);
    acc += __shfl_xor(acc, 4);
    if (grp == 0) out[(size_t)n * HD + h] = acc;
  }
}

extern "C" void kernel_launch(void* const* d_in, const int* in_sizes, int n_in,
                              void* d_out, int out_size, void* d_ws, size_t ws_size,
                              hipStream_t stream) {
  (void)in_sizes; (void)n_in; (void)out_size; (void)ws_size;
  const float* hs = (const float*)d_in[0];
  const float* W  = (const float*)d_in[1];
  const float* b  = (const float*)d_in[2];
  const float* c  = (const float*)d_in[3];
  float* out = (float*)d_out;

  float* align_ws = (float*)d_ws;                                  // 2 MB
  short* Wtb16 = (short*)((char*)d_ws + (size_t)NB * SD * 4);      // 512 KB

  wconv_kernel<<<256, 256, 0, stream>>>(W, Wtb16);
  align_kernel<<<NB * 4, 512, 0, stream>>>(hs, Wtb16, b, c, align_ws);
  ctx_kernel<<<NB, 256, 0, stream>>>(hs, align_ws, out);
}

// Round 11
// 714.178 us; speedup vs baseline: 1.3231x; 1.1290x over previous
//
#include <hip/hip_runtime.h>
#include <hip/hip_bf16.h>
#include <stdint.h>
#include <stddef.h>

typedef __attribute__((ext_vector_type(8))) short short8;
typedef __attribute__((ext_vector_type(4))) float f32x4;
typedef __attribute__((ext_vector_type(16))) float f32x16;

#define NB 2048
#define HD 512
#define SD 256

#define AROW 516   // shorts per s-row (512 k + 4 pad): 1032 B stride -> bank
                   // step 258 mod 32 = 2 -> 2 lanes/bank on all reads = free

__device__ __forceinline__ short f2bf(float x) {
  __hip_bfloat16 h = __float2bfloat16(x);
  return *reinterpret_cast<short*>(&h);
}

__device__ __forceinline__ float fast_tanh(float x) {
  x = fminf(fmaxf(x, -15.f), 15.f);
  float e = __expf(2.f * x);
  return __fdividef(e - 1.f, e + 1.f);
}

// ---- Wtb16[kb][j][kk] = bf16(W[kb*16+kk][j]), kb in [0,32) ----
__global__ __launch_bounds__(256) void wconv_kernel(const float* __restrict__ W,
                                                    short* __restrict__ Wtb16) {
  __shared__ float tile[32][33];
  const int bx = blockIdx.x;
  const int tk0 = (bx & 15) * 32;
  const int tj0 = (bx >> 4) * 32;
  const int lx = threadIdx.x & 31;
  const int ly = threadIdx.x >> 5;
  for (int r = 0; r < 4; ++r) {
    int yy = ly + r * 8;
    tile[yy][lx] = W[(size_t)(tk0 + yy) * HD + tj0 + lx];
  }
  __syncthreads();
  for (int r = 0; r < 4; ++r) {
    int yy = ly + r * 8;
    const int k = tk0 + lx;
    Wtb16[(size_t)(k >> 4) * (HD * 16) + (size_t)(tj0 + yy) * 16 + (k & 15)] =
        f2bf(tile[lx][yy]);
  }
}

// ---- alignment[n][s] = sum_j tanh( sum_k hs[n,k,s]*W[k,j] + b[j] ) * c[j] ----
// Block = 64 s x FULL 512 j, 512 threads = 8 waves (disjoint 64-j strips).
// Phase 1: stage the ENTIRE A-panel (64s x 512k bf16, 66 KB) into LDS once —
// a pure HBM-streaming burst (128 KB/block, fully pipelined scalar loads).
// ONE barrier. Phase 2: 32 k-blocks, NO barriers, NO re-staging: W fragments
// straight from L2-resident Wtb16 (contiguous 1 KB wave-reads, disjoint j ->
// zero amplification vs LDS staging), A fragments from read-only LDS.
// acc[2][2] f32x16 = 64 AGPR, ~100 regs total -> 2 blocks/CU (LDS-capped):
// the co-resident block's MFMA phase overlaps this block's staging burst.
__global__ void __launch_bounds__(512, 4)
align_kernel(const float* __restrict__ hs, const short* __restrict__ Wtb16,
             const float* __restrict__ bias, const float* __restrict__ ctxv,
             float* __restrict__ align_out)
{
  __shared__ short As[64 * AROW];   // 66 KB
  __shared__ float abuf[64];

  const int tid = threadIdx.x;
  const int n = blockIdx.x >> 2;
  const int s0 = (blockIdx.x & 3) * 64;
  const float* hsn = hs + (size_t)n * (HD * SD) + s0;

  if (tid < 64) abuf[tid] = 0.f;

  // ---- phase 1: stage A-panel. thread -> (s = tid&63, k-range 64 of tid>>6)
  {
    const int a_s = tid & 63;
    const int a_kg = tid >> 6;          // wave id = k-group
    #pragma unroll
    for (int o = 0; o < 8; ++o) {
      const int k0 = a_kg * 64 + o * 8;
      const float* src = hsn + (size_t)k0 * SD + a_s;
      short8 pk;
      #pragma unroll
      for (int e = 0; e < 8; ++e) pk[e] = f2bf(src[(size_t)e * SD]);
      *(short8*)&As[a_s * AROW + k0] = pk;
    }
  }
  __syncthreads();

  // ---- phase 2: barrier-free MFMA loop
  const int lane = tid & 63;
  const int wid = tid >> 6;
  const int jb = wid * 64;
  const int l31 = lane & 31;
  const int hg = lane >> 5;             // k-half within 16: k = hg*8 + e

  f32x16 acc[2][2];
  #pragma unroll
  for (int i = 0; i < 2; ++i)
    #pragma unroll
    for (int p = 0; p < 2; ++p)
      #pragma unroll
      for (int q = 0; q < 16; ++q) acc[i][p][q] = 0.f;

  const short* wlane = Wtb16 + (size_t)(jb + l31) * 16 + hg * 8;
  const int afo = l31 * AROW + hg * 8;  // + i*32*AROW + kb*16

  #pragma unroll 4
  for (int kb = 0; kb < 32; ++kb) {
    const short* wk = wlane + (size_t)kb * (HD * 16);
    short8 wf0 = *(const short8*)(wk);
    short8 wf1 = *(const short8*)(wk + 32 * 16);
    short8 af0 = *(const short8*)&As[afo + kb * 16];
    short8 af1 = *(const short8*)&As[afo + 32 * AROW + kb * 16];

    __builtin_amdgcn_s_setprio(1);
    acc[0][0] = __builtin_amdgcn_mfma_f32_32x32x16_bf16(wf0, af0, acc[0][0], 0, 0, 0);
    acc[0][1] = __builtin_amdgcn_mfma_f32_32x32x16_bf16(wf1, af0, acc[0][1], 0, 0, 0);
    acc[1][0] = __builtin_amdgcn_mfma_f32_32x32x16_bf16(wf0, af1, acc[1][0], 0, 0, 0);
    acc[1][1] = __builtin_amdgcn_mfma_f32_32x32x16_bf16(wf1, af1, acc[1][1], 0, 0, 0);
    __builtin_amdgcn_s_setprio(0);
  }

  // epilogue: D col = s = l31 (+i*32), row(q) = (q&3) + 8*(q>>2) + 4*hg (+p*32)
  float part0 = 0.f, part1 = 0.f;
  #pragma unroll
  for (int p = 0; p < 2; ++p) {
    const int jfr = jb + p * 32 + hg * 4;
    #pragma unroll
    for (int g = 0; g < 4; ++g) {
      const int j4 = jfr + g * 8;
      f32x4 bv = *(const f32x4*)(bias + j4);
      f32x4 cv = *(const f32x4*)(ctxv + j4);
      #pragma unroll
      for (int r = 0; r < 4; ++r) {
        const int q = g * 4 + r;
        part0 += fast_tanh(acc[0][p][q] + bv[r]) * cv[r];
        part1 += fast_tanh(acc[1][p][q] + bv[r]) * cv[r];
      }
    }
  }
  part0 += __shfl_xor(part0, 32);
  part1 += __shfl_xor(part1, 32);
  if (lane < 32) {
    atomicAdd(&abuf[l31], part0);
    atomicAdd(&abuf[32 + l31], part1);
  }
  __syncthreads();
  if (tid < 64) align_out[(size_t)n * SD + s0 + tid] = abuf[tid];
}

// ---- softmax over s + context[n,h] = sum_s attn[s]*hs[n,h,s] ----
__global__ __launch_bounds__(256) void ctx_kernel(const float* __restrict__ hs,
                                                  const float* __restrict__ align_in,
                                                  float* __restrict__ out)
{
  __shared__ __align__(16) float attn_s[256];
  __shared__ float red[8];
  const int n = blockIdx.x;
  const int t = threadIdx.x;
  const int lane = t & 63, wid = t >> 6;

  float a = align_in[(size_t)n * 256 + t];
  float m = a;
  #pragma unroll
  for (int off = 32; off; off >>= 1) m = fmaxf(m, __shfl_xor(m, off));
  if (lane == 0) red[wid] = m;
  __syncthreads();
  m = fmaxf(fmaxf(red[0], red[1]), fmaxf(red[2], red[3]));
  float e = __expf(a - m);
  float s = e;
  #pragma unroll
  for (int off = 32; off; off >>= 1) s += __shfl_xor(s, off);
  if (lane == 0) red[4 + wid] = s;
  __syncthreads();
  s = red[4] + red[5] + red[6] + red[7];
  attn_s[t] = e / s;
  __syncthreads();

  const int grp = t & 7;      // s-chunk of 32
  const int hrow = t >> 3;    // 0..31
  float av[32];
  #pragma unroll
  for (int u = 0; u < 8; ++u) {
    float4 v = *(const float4*)&attn_s[grp * 32 + u * 4];
    av[4*u+0] = v.x; av[4*u+1] = v.y; av[4*u+2] = v.z; av[4*u+3] = v.w;
  }
  const float* hb = hs + (size_t)n * (HD * SD) + grp * 32;
  for (int it = 0; it < 16; ++it) {
    const int h = it * 32 + hrow;
    const float4* p = (const float4*)(hb + (size_t)h * SD);
    float acc = 0.f;
    #pragma unroll
    for (int u = 0; u < 8; ++u) {
      float4 v = p[u];
      acc += av[4*u+0]*v.x + av[4*u+1]*v.y + av[4*u+2]*v.z + av[4*u+3]*v.w;
    }
    acc += __shfl_xor(acc, 1);
    acc += __shfl_xor(acc, 2);
    acc += __shfl_xor(acc, 4);
    if (grp == 0) out[(size_t)n * HD + h] = acc;
  }
}

extern "C" void kernel_launch(void* const* d_in, const int* in_sizes, int n_in,
                              void* d_out, int out_size, void* d_ws, size_t ws_size,
                              hipStream_t stream) {
  (void)in_sizes; (void)n_in; (void)out_size; (void)ws_size;
  const float* hs = (const float*)d_in[0];
  const float* W  = (const float*)d_in[1];
  const float* b  = (const float*)d_in[2];
  const float* c  = (const float*)d_in[3];
  float* out = (float*)d_out;

  float* align_ws = (float*)d_ws;                                  // 2 MB
  short* Wtb16 = (short*)((char*)d_ws + (size_t)NB * SD * 4);      // 512 KB

  wconv_kernel<<<256, 256, 0, stream>>>(W, Wtb16);
  align_kernel<<<NB * 4, 512, 0, stream>>>(hs, Wtb16, b, c, align_ws);
  ctx_kernel<<<NB, 256, 0, stream>>>(hs, align_ws, out);
}

// Round 12
// 681.812 us; speedup vs baseline: 1.3859x; 1.0475x over previous
//
#include <hip/hip_runtime.h>
#include <hip/hip_bf16.h>
#include <stdint.h>
#include <stddef.h>

typedef __attribute__((ext_vector_type(8))) short short8;
typedef __attribute__((ext_vector_type(4))) float f32x4;
typedef __attribute__((ext_vector_type(16))) float f32x16;

#define NB 2048
#define HD 512
#define SD 256

#define AROW 516   // shorts per s-row (512 k + 4 pad): bank step 258%32=2 ->
                   // 2 lanes/bank on all b128 reads/writes = conflict-free

__device__ __forceinline__ short f2bf(float x) {
  __hip_bfloat16 h = __float2bfloat16(x);
  return *reinterpret_cast<short*>(&h);
}

__device__ __forceinline__ float fast_tanh(float x) {
  x = fminf(fmaxf(x, -15.f), 15.f);
  float e = __expf(2.f * x);
  return __fdividef(e - 1.f, e + 1.f);
}

// ---- Wtb16[kb][j][kk] = bf16(W[kb*16+kk][j]), kb in [0,32) ----
__global__ __launch_bounds__(256) void wconv_kernel(const float* __restrict__ W,
                                                    short* __restrict__ Wtb16) {
  __shared__ float tile[32][33];
  const int bx = blockIdx.x;
  const int tk0 = (bx & 15) * 32;
  const int tj0 = (bx >> 4) * 32;
  const int lx = threadIdx.x & 31;
  const int ly = threadIdx.x >> 5;
  for (int r = 0; r < 4; ++r) {
    int yy = ly + r * 8;
    tile[yy][lx] = W[(size_t)(tk0 + yy) * HD + tj0 + lx];
  }
  __syncthreads();
  for (int r = 0; r < 4; ++r) {
    int yy = ly + r * 8;
    const int k = tk0 + lx;
    Wtb16[(size_t)(k >> 4) * (HD * 16) + (size_t)(tj0 + yy) * 16 + (k & 15)] =
        f2bf(tile[lx][yy]);
  }
}

// ---- alignment[n][s] = sum_j tanh( sum_k hs[n,k,s]*W[k,j] + b[j] ) * c[j] ----
// Block = 64 s x FULL 512 j, 512 threads = 8 waves (disjoint 64-j strips).
// Phase 1: stage entire A-panel (64s x 512k bf16, 66 KB LDS) once; ONE barrier.
// Phase 2: barrier-free k-loop with EXPLICIT register pipelining:
//   W: 3-deep named ring (prefetch kb+3 issued after the MFMA cluster that
//      consumed slot kb%3 -> ~3 k-blocks of L2-latency cover),
//   A: 2-deep ring from read-only LDS.
// Full unroll keeps every ring index compile-time constant (rule #20).
// acc 64 + wb 24 + ab 16 + addr ~ 120 VGPR -> 4 waves/SIMD, 2 blocks/CU:
// one block's phase-1 HBM burst overlaps the other's phase-2 MFMA.
__global__ void __launch_bounds__(512, 4)
align_kernel(const float* __restrict__ hs, const short* __restrict__ Wtb16,
             const float* __restrict__ bias, const float* __restrict__ ctxv,
             float* __restrict__ align_out)
{
  __shared__ short As[64 * AROW];   // 66 KB
  __shared__ float abuf[64];

  const int tid = threadIdx.x;
  const int n = blockIdx.x >> 2;
  const int s0 = (blockIdx.x & 3) * 64;
  const float* hsn = hs + (size_t)n * (HD * SD) + s0;

  if (tid < 64) abuf[tid] = 0.f;

  // ---- phase 1: stage A-panel. thread -> (s = tid&63, 64-k range of tid>>6)
  {
    const int a_s = tid & 63;
    const int a_kg = tid >> 6;
    #pragma unroll
    for (int o = 0; o < 8; ++o) {
      const int k0 = a_kg * 64 + o * 8;
      const float* src = hsn + (size_t)k0 * SD + a_s;
      short8 pk;
      #pragma unroll
      for (int e = 0; e < 8; ++e) pk[e] = f2bf(src[(size_t)e * SD]);
      *(short8*)&As[a_s * AROW + k0] = pk;
    }
  }
  __syncthreads();

  // ---- phase 2: barrier-free MFMA loop, explicit reg-ring pipelines
  const int lane = tid & 63;
  const int wid = tid >> 6;
  const int jb = wid * 64;
  const int l31 = lane & 31;
  const int hg = lane >> 5;             // k-half within 16: k = hg*8 + e

  f32x16 acc[2][2];
  #pragma unroll
  for (int i = 0; i < 2; ++i)
    #pragma unroll
    for (int p = 0; p < 2; ++p)
      #pragma unroll
      for (int q = 0; q < 16; ++q) acc[i][p][q] = 0.f;

  const short* wlane = Wtb16 + (size_t)(jb + l31) * 16 + hg * 8;
  const int afo = l31 * AROW + hg * 8;

  short8 wb[3][2];   // W ring, 3 deep
  short8 ab[2][2];   // A ring, 2 deep

  #pragma unroll
  for (int d = 0; d < 3; ++d) {
    const short* wk = wlane + (size_t)d * (HD * 16);
    wb[d][0] = *(const short8*)(wk);
    wb[d][1] = *(const short8*)(wk + 32 * 16);
  }
  #pragma unroll
  for (int d = 0; d < 2; ++d) {
    ab[d][0] = *(const short8*)&As[afo + d * 16];
    ab[d][1] = *(const short8*)&As[afo + 32 * AROW + d * 16];
  }

  #pragma unroll
  for (int kb = 0; kb < 32; ++kb) {
    const int ws = kb % 3;
    const int as = kb & 1;

    __builtin_amdgcn_s_setprio(1);
    acc[0][0] = __builtin_amdgcn_mfma_f32_32x32x16_bf16(wb[ws][0], ab[as][0], acc[0][0], 0, 0, 0);
    acc[0][1] = __builtin_amdgcn_mfma_f32_32x32x16_bf16(wb[ws][1], ab[as][0], acc[0][1], 0, 0, 0);
    acc[1][0] = __builtin_amdgcn_mfma_f32_32x32x16_bf16(wb[ws][0], ab[as][1], acc[1][0], 0, 0, 0);
    acc[1][1] = __builtin_amdgcn_mfma_f32_32x32x16_bf16(wb[ws][1], ab[as][1], acc[1][1], 0, 0, 0);
    __builtin_amdgcn_s_setprio(0);

    // refill the just-consumed slots (issued after the MFMAs -> no WAR stall)
    if (kb < 29) {
      const short* wk = wlane + (size_t)(kb + 3) * (HD * 16);
      wb[ws][0] = *(const short8*)(wk);
      wb[ws][1] = *(const short8*)(wk + 32 * 16);
    }
    if (kb < 30) {
      ab[as][0] = *(const short8*)&As[afo + (kb + 2) * 16];
      ab[as][1] = *(const short8*)&As[afo + 32 * AROW + (kb + 2) * 16];
    }
  }

  // epilogue: D col = s = l31 (+i*32), row(q) = (q&3) + 8*(q>>2) + 4*hg (+p*32)
  float part0 = 0.f, part1 = 0.f;
  #pragma unroll
  for (int p = 0; p < 2; ++p) {
    const int jfr = jb + p * 32 + hg * 4;
    #pragma unroll
    for (int g = 0; g < 4; ++g) {
      const int j4 = jfr + g * 8;
      f32x4 bv = *(const f32x4*)(bias + j4);
      f32x4 cv = *(const f32x4*)(ctxv + j4);
      #pragma unroll
      for (int r = 0; r < 4; ++r) {
        const int q = g * 4 + r;
        part0 += fast_tanh(acc[0][p][q] + bv[r]) * cv[r];
        part1 += fast_tanh(acc[1][p][q] + bv[r]) * cv[r];
      }
    }
  }
  part0 += __shfl_xor(part0, 32);
  part1 += __shfl_xor(part1, 32);
  if (lane < 32) {
    atomicAdd(&abuf[l31], part0);
    atomicAdd(&abuf[32 + l31], part1);
  }
  __syncthreads();
  if (tid < 64) align_out[(size_t)n * SD + s0 + tid] = abuf[tid];
}

// ---- softmax over s + context[n,h] = sum_s attn[s]*hs[n,h,s] ----
__global__ __launch_bounds__(256) void ctx_kernel(const float* __restrict__ hs,
                                                  const float* __restrict__ align_in,
                                                  float* __restrict__ out)
{
  __shared__ __align__(16) float attn_s[256];
  __shared__ float red[8];
  const int n = blockIdx.x;
  const int t = threadIdx.x;
  const int lane = t & 63, wid = t >> 6;

  float a = align_in[(size_t)n * 256 + t];
  float m = a;
  #pragma unroll
  for (int off = 32; off; off >>= 1) m = fmaxf(m, __shfl_xor(m, off));
  if (lane == 0) red[wid] = m;
  __syncthreads();
  m = fmaxf(fmaxf(red[0], red[1]), fmaxf(red[2], red[3]));
  float e = __expf(a - m);
  float s = e;
  #pragma unroll
  for (int off = 32; off; off >>= 1) s += __shfl_xor(s, off);
  if (lane == 0) red[4 + wid] = s;
  __syncthreads();
  s = red[4] + red[5] + red[6] + red[7];
  attn_s[t] = e / s;
  __syncthreads();

  const int grp = t & 7;      // s-chunk of 32
  const int hrow = t >> 3;    // 0..31
  float av[32];
  #pragma unroll
  for (int u = 0; u < 8; ++u) {
    float4 v = *(const float4*)&attn_s[grp * 32 + u * 4];
    av[4*u+0] = v.x; av[4*u+1] = v.y; av[4*u+2] = v.z; av[4*u+3] = v.w;
  }
  const float* hb = hs + (size_t)n * (HD * SD) + grp * 32;
  for (int it = 0; it < 16; ++it) {
    const int h = it * 32 + hrow;
    const float4* p = (const float4*)(hb + (size_t)h * SD);
    float acc = 0.f;
    #pragma unroll
    for (int u = 0; u < 8; ++u) {
      float4 v = p[u];
      acc += av[4*u+0]*v.x + av[4*u+1]*v.y + av[4*u+2]*v.z + av[4*u+3]*v.w;
    }
    acc += __shfl_xor(acc, 1);
    acc += __shfl_xor(acc, 2);
    acc += __shfl_xor(acc, 4);
    if (grp == 0) out[(size_t)n * HD + h] = acc;
  }
}

extern "C" void kernel_launch(void* const* d_in, const int* in_sizes, int n_in,
                              void* d_out, int out_size, void* d_ws, size_t ws_size,
                              hipStream_t stream) {
  (void)in_sizes; (void)n_in; (void)out_size; (void)ws_size;
  const float* hs = (const float*)d_in[0];
  const float* W  = (const float*)d_in[1];
  const float* b  = (const float*)d_in[2];
  const float* c  = (const float*)d_in[3];
  float* out = (float*)d_out;

  float* align_ws = (float*)d_ws;                                  // 2 MB
  short* Wtb16 = (short*)((char*)d_ws + (size_t)NB * SD * 4);      // 512 KB

  wconv_kernel<<<256, 256, 0, stream>>>(W, Wtb16);
  align_kernel<<<NB * 4, 512, 0, stream>>>(hs, Wtb16, b, c, align_ws);
  ctx_kernel<<<NB, 256, 0, stream>>>(hs, align_ws, out);
}